// Round 3
// baseline (4174.478 us; speedup 1.0000x reference)
//
#include <hip/hip_runtime.h>
#include <math.h>

// Problem constants (reference: B=512, S=512, D_IN=D_OUT=256, fp32)
#define S_LEN 512
#define B_SZ  512
#define D_DIM 256

// Fast, robust tanh: 1 - 2/(e^{2x}+1).
__device__ __forceinline__ float tanh_fast(float x) {
    float e = __expf(2.0f * x);
    return 1.0f - 2.0f / (e + 1.0f);
}

// ---------------------------------------------------------------------------
// Phase 1: Z[b,t,:] = x[b,t,:] @ Wx[t]   (Z written into d_out, fp32)
// grid (S, B/16), block 256. Thread j owns output column j for 16 batch rows.
// v2: rolling register double-buffer for w (groups of 8 k) so loads for the
// next group are in flight during the current group's FMAs; xs read as
// float4 along k (1 LDS issue per 4 FMAs instead of 1 per 1).
// ---------------------------------------------------------------------------
__global__ __launch_bounds__(256) void phase1_xwx(const float* __restrict__ x,
                                                  const float* __restrict__ Wx,
                                                  float* __restrict__ Z) {
    const int t  = blockIdx.x;
    const int b0 = blockIdx.y * 16;
    const int j  = threadIdx.x;

    __shared__ float xs[16][D_DIM];  // 16 KB

    // Cooperative load of the x tile: 16 rows x 256 cols = 1024 float4s.
    #pragma unroll
    for (int r4 = 0; r4 < 4; ++r4) {
        int idx = r4 * 256 + j;          // [0, 1024)
        int r   = idx >> 6;              // row 0..15
        int c4  = (idx & 63) * 4;        // col base
        *(float4*)&xs[r][c4] =
            *(const float4*)(x + ((size_t)(b0 + r) * S_LEN + t) * D_DIM + c4);
    }
    __syncthreads();

    float acc[16];
    #pragma unroll
    for (int r = 0; r < 16; ++r) acc[r] = 0.0f;

    const float* wp = Wx + (size_t)t * D_DIM * D_DIM + j;

    float wA[8], wB[8];
    #pragma unroll
    for (int i = 0; i < 8; ++i) wA[i] = wp[(size_t)i * D_DIM];

    // 16 iterations x 16 k each (two 8-k groups, ping-pong wA/wB).
    for (int kb = 0; kb < D_DIM; kb += 16) {
        // prefetch group kb+8 into wB
        #pragma unroll
        for (int i = 0; i < 8; ++i) wB[i] = wp[(size_t)(kb + 8 + i) * D_DIM];
        // FMA group kb from wA  (k ascending — same summation order as before)
        #pragma unroll
        for (int kk = 0; kk < 8; kk += 4) {
            #pragma unroll
            for (int r = 0; r < 16; ++r) {
                const float4 xv = *(const float4*)&xs[r][kb + kk];
                acc[r] = fmaf(xv.x, wA[kk + 0], acc[r]);
                acc[r] = fmaf(xv.y, wA[kk + 1], acc[r]);
                acc[r] = fmaf(xv.z, wA[kk + 2], acc[r]);
                acc[r] = fmaf(xv.w, wA[kk + 3], acc[r]);
            }
        }
        // prefetch group kb+16 into wA (skip on last iter)
        if (kb + 16 < D_DIM) {
            #pragma unroll
            for (int i = 0; i < 8; ++i) wA[i] = wp[(size_t)(kb + 16 + i) * D_DIM];
        }
        // FMA group kb+8 from wB
        #pragma unroll
        for (int kk = 0; kk < 8; kk += 4) {
            #pragma unroll
            for (int r = 0; r < 16; ++r) {
                const float4 xv = *(const float4*)&xs[r][kb + 8 + kk];
                acc[r] = fmaf(xv.x, wB[kk + 0], acc[r]);
                acc[r] = fmaf(xv.y, wB[kk + 1], acc[r]);
                acc[r] = fmaf(xv.z, wB[kk + 2], acc[r]);
                acc[r] = fmaf(xv.w, wB[kk + 3], acc[r]);
            }
        }
    }

    float* zp = Z + ((size_t)b0 * S_LEN + t) * D_DIM + j;
    #pragma unroll
    for (int r = 0; r < 16; ++r) zp[(size_t)r * S_LEN * D_DIM] = acc[r];
}

// ---------------------------------------------------------------------------
// Phase 2 inner helper: 8-k FMA group. h read as b128 (2 per m per group).
// k ascending within the slice — identical summation order to the passing run.
// ---------------------------------------------------------------------------
__device__ __forceinline__ void fma_group(const float4* __restrict__ w, int kb,
                                          const float (*hs)[D_DIM],
                                          float4* __restrict__ acc) {
    #pragma unroll
    for (int q = 0; q < 2; ++q) {
        #pragma unroll
        for (int m = 0; m < 4; ++m) {
            const float4 hv = *(const float4*)&hs[m][kb + q * 4];
            const float4 w0 = w[q * 4 + 0];
            const float4 w1 = w[q * 4 + 1];
            const float4 w2 = w[q * 4 + 2];
            const float4 w3 = w[q * 4 + 3];
            acc[m].x = fmaf(hv.x, w0.x, acc[m].x);
            acc[m].y = fmaf(hv.x, w0.y, acc[m].y);
            acc[m].z = fmaf(hv.x, w0.z, acc[m].z);
            acc[m].w = fmaf(hv.x, w0.w, acc[m].w);
            acc[m].x = fmaf(hv.y, w1.x, acc[m].x);
            acc[m].y = fmaf(hv.y, w1.y, acc[m].y);
            acc[m].z = fmaf(hv.y, w1.z, acc[m].z);
            acc[m].w = fmaf(hv.y, w1.w, acc[m].w);
            acc[m].x = fmaf(hv.z, w2.x, acc[m].x);
            acc[m].y = fmaf(hv.z, w2.y, acc[m].y);
            acc[m].z = fmaf(hv.z, w2.z, acc[m].z);
            acc[m].w = fmaf(hv.z, w2.w, acc[m].w);
            acc[m].x = fmaf(hv.w, w3.x, acc[m].x);
            acc[m].y = fmaf(hv.w, w3.y, acc[m].y);
            acc[m].z = fmaf(hv.w, w3.z, acc[m].z);
            acc[m].w = fmaf(hv.w, w3.w, acc[m].w);
        }
    }
}

// ---------------------------------------------------------------------------
// Phase 2: sequential scan. Block g owns batches 4g..4g+3, t=0..511 private.
//   h_t = tanh(Z[:,t,:] + h_{t-1} @ Wh[t]);  h written over Z in d_out.
//
// v3 vs round-1 version:
//  * Rolling register double-buffer (A/B, 8 float4 each) for the Wh stream,
//    prefetch distance crosses the step boundary: group-3's FMAs run while
//    next step's group-0 loads (+ next Z) are already in flight.
//  * Raw s_barrier + explicit lgkmcnt(0)-only waits replace __syncthreads.
//    __syncthreads drains vmcnt(0) (global store in flight), killing the
//    cross-step pipeline. LDS visibility (red, h) only needs lgkmcnt(0);
//    the global output store has no in-kernel cross-thread reader (each
//    thread reads/writes only its own Z positions), so no vmcnt drain needed.
//  * h consumed as ds_read_b128 (8/group instead of 32 b32).
// ---------------------------------------------------------------------------
__global__ __launch_bounds__(512) void phase2_scan(const float* __restrict__ Wh,
                                                   float* __restrict__ ZH) {
    const int g   = blockIdx.x;
    const int b0  = g * 4;
    const int tid = threadIdx.x;
    // k-loop mapping
    const int c4  = (tid & 63) * 4;   // column base (0..252)
    const int ks  = tid >> 6;         // k-slice 0..7 (wave-uniform)
    const int kbase = ks * 32;
    // reduce-phase mapping
    const int rm  = tid >> 7;         // batch 0..3 (wave-uniform)
    const int rc  = (tid & 127) * 2;  // column base (0..254)

    __shared__ float h[4][D_DIM];        // 4 KB   hidden state
    __shared__ float red[8][4][D_DIM];   // 32 KB  partial-sum exchange

    for (int i = tid; i < 4 * D_DIM; i += 512) ((float*)h)[i] = 0.0f;
    __syncthreads();

    float* zrow = ZH + ((size_t)(b0 + rm) * S_LEN) * D_DIM + rc;
    const float* wbase = Wh + c4;

    float4 A[8], Bv[8];
    // prologue: step-0 group-0 weights + step-0 Z in flight before the loop
    #pragma unroll
    for (int i = 0; i < 8; ++i)
        A[i] = *(const float4*)(wbase + (size_t)(kbase + i) * D_DIM);
    float2 z = *(const float2*)(zrow);

    for (int t = 0; t < S_LEN; ++t) {
        const float* wt = wbase + (size_t)t * D_DIM * D_DIM;
        const int tn = (t + 1 < S_LEN) ? t + 1 : t;   // last iter: dummy reload
        const float* wn = wbase + (size_t)tn * D_DIM * D_DIM;

        float4 acc[4];
        #pragma unroll
        for (int m = 0; m < 4; ++m) acc[m] = make_float4(0.f, 0.f, 0.f, 0.f);

        // group 0 (A) | prefetch group 1 -> B
        #pragma unroll
        for (int i = 0; i < 8; ++i)
            Bv[i] = *(const float4*)(wt + (size_t)(kbase + 8 + i) * D_DIM);
        fma_group(A, kbase + 0, h, acc);

        // group 1 (B) | prefetch group 2 -> A
        #pragma unroll
        for (int i = 0; i < 8; ++i)
            A[i] = *(const float4*)(wt + (size_t)(kbase + 16 + i) * D_DIM);
        fma_group(Bv, kbase + 8, h, acc);

        // group 2 (A) | prefetch group 3 -> B
        #pragma unroll
        for (int i = 0; i < 8; ++i)
            Bv[i] = *(const float4*)(wt + (size_t)(kbase + 24 + i) * D_DIM);
        fma_group(A, kbase + 16, h, acc);

        // group 3 (B) | prefetch NEXT STEP group 0 -> A, and next Z
        #pragma unroll
        for (int i = 0; i < 8; ++i)
            A[i] = *(const float4*)(wn + (size_t)(kbase + i) * D_DIM);
        const float2 zn = *(const float2*)(zrow + (size_t)tn * D_DIM);
        fma_group(Bv, kbase + 24, h, acc);

        // publish partials (contiguous b128, conflict-free)
        #pragma unroll
        for (int m = 0; m < 4; ++m)
            *(float4*)&red[ks][m][c4] = acc[m];

        // LDS-only drain + raw barrier: weight/Z loads stay in flight
        asm volatile("s_waitcnt lgkmcnt(0)" ::: "memory");
        __builtin_amdgcn_s_barrier();
        __builtin_amdgcn_sched_barrier(0);

        // balanced reduce: each thread owns (rm, rc..rc+1)
        float sx = z.x, sy = z.y;
        #pragma unroll
        for (int s = 0; s < 8; ++s) {
            const float2 p = *(const float2*)&red[s][rm][rc];
            sx += p.x; sy += p.y;
        }
        const float hx = tanh_fast(sx);
        const float hy = tanh_fast(sy);
        *(float2*)&h[rm][rc] = make_float2(hx, hy);                    // state
        *(float2*)(zrow + (size_t)t * D_DIM) = make_float2(hx, hy);    // output
        z = zn;

        asm volatile("s_waitcnt lgkmcnt(0)" ::: "memory");
        __builtin_amdgcn_s_barrier();
        __builtin_amdgcn_sched_barrier(0);
    }
}

// ---------------------------------------------------------------------------
extern "C" void kernel_launch(void* const* d_in, const int* in_sizes, int n_in,
                              void* d_out, int out_size, void* d_ws, size_t ws_size,
                              hipStream_t stream) {
    const float* x  = (const float*)d_in[0];   // [B, S, D_IN]
    const float* Wx = (const float*)d_in[1];   // [S, D_IN, D_OUT]
    const float* Wh = (const float*)d_in[2];   // [S, D_OUT, D_OUT]
    float* out = (float*)d_out;                // [B, S, D_OUT]

    // Phase 1: Z = batched x @ Wx  -> d_out
    phase1_xwx<<<dim3(S_LEN, B_SZ / 16), 256, 0, stream>>>(x, Wx, out);
    // Phase 2: sequential scan over t, in-place h over Z in d_out
    phase2_scan<<<dim3(B_SZ / 4), 512, 0, stream>>>(Wh, out);
}

// Round 4
// 3124.582 us; speedup vs baseline: 1.3360x; 1.3360x over previous
//
#include <hip/hip_runtime.h>
#include <math.h>

// Problem constants (reference: B=512, S=512, D_IN=D_OUT=256, fp32)
#define S_LEN 512
#define B_SZ  512
#define D_DIM 256

// Fast, robust tanh: 1 - 2/(e^{2x}+1).
__device__ __forceinline__ float tanh_fast(float x) {
    float e = __expf(2.0f * x);
    return 1.0f - 2.0f / (e + 1.0f);
}

// ---------------------------------------------------------------------------
// Phase 1: Z[b,t,:] = x[b,t,:] @ Wx[t]   (Z written into d_out, fp32)
// grid (S, B/16), block 256 = 64 col-groups x 4 k-slices.
// v3: thread owns 4 columns (float4 w loads, 1KB/wave contiguous) and a
// 64-wide k-slice. One xs ds_read_b128 now feeds 16 FMAs (was 4) -> LDS
// issue no longer rivals FMA issue. 4-slice partial sums reduced via LDS.
// LDS 80KB -> 2 blocks/CU.
// ---------------------------------------------------------------------------
__global__ __launch_bounds__(256, 2) void phase1_xwx(const float* __restrict__ x,
                                                     const float* __restrict__ Wx,
                                                     float* __restrict__ Z) {
    const int t   = blockIdx.x;
    const int b0  = blockIdx.y * 16;
    const int tid = threadIdx.x;
    const int c4  = (tid & 63) * 4;   // column base (0..252)
    const int ks  = tid >> 6;         // k-slice 0..3 (wave-uniform)
    const int kbase = ks * 64;

    __shared__ float xs[16][D_DIM];       // 16 KB
    __shared__ float red[4][16][D_DIM];   // 64 KB partial sums

    // Cooperative stage of the x tile: 16 rows x 256 cols = 1024 float4s.
    #pragma unroll
    for (int r4 = 0; r4 < 4; ++r4) {
        int idx = r4 * 256 + tid;        // [0, 1024)
        int r   = idx >> 6;              // row 0..15
        int cc  = (idx & 63) * 4;        // col base
        *(float4*)&xs[r][cc] =
            *(const float4*)(x + ((size_t)(b0 + r) * S_LEN + t) * D_DIM + cc);
    }
    __syncthreads();

    float4 acc[16];
    #pragma unroll
    for (int r = 0; r < 16; ++r) acc[r] = make_float4(0.f, 0.f, 0.f, 0.f);

    const float* wp = Wx + (size_t)t * D_DIM * D_DIM + c4;

    // 16 iters x 4 k each. k ascending per output => stable summation order.
    #pragma unroll 2
    for (int k4 = 0; k4 < 16; ++k4) {
        const int k = kbase + k4 * 4;
        const float4 w0 = *(const float4*)(wp + (size_t)(k + 0) * D_DIM);
        const float4 w1 = *(const float4*)(wp + (size_t)(k + 1) * D_DIM);
        const float4 w2 = *(const float4*)(wp + (size_t)(k + 2) * D_DIM);
        const float4 w3 = *(const float4*)(wp + (size_t)(k + 3) * D_DIM);
        #pragma unroll
        for (int r = 0; r < 16; ++r) {
            const float4 xv = *(const float4*)&xs[r][k];  // wave-uniform bcast
            acc[r].x = fmaf(xv.x, w0.x, acc[r].x);
            acc[r].y = fmaf(xv.x, w0.y, acc[r].y);
            acc[r].z = fmaf(xv.x, w0.z, acc[r].z);
            acc[r].w = fmaf(xv.x, w0.w, acc[r].w);
            acc[r].x = fmaf(xv.y, w1.x, acc[r].x);
            acc[r].y = fmaf(xv.y, w1.y, acc[r].y);
            acc[r].z = fmaf(xv.y, w1.z, acc[r].z);
            acc[r].w = fmaf(xv.y, w1.w, acc[r].w);
            acc[r].x = fmaf(xv.z, w2.x, acc[r].x);
            acc[r].y = fmaf(xv.z, w2.y, acc[r].y);
            acc[r].z = fmaf(xv.z, w2.z, acc[r].z);
            acc[r].w = fmaf(xv.z, w2.w, acc[r].w);
            acc[r].x = fmaf(xv.w, w3.x, acc[r].x);
            acc[r].y = fmaf(xv.w, w3.y, acc[r].y);
            acc[r].z = fmaf(xv.w, w3.z, acc[r].z);
            acc[r].w = fmaf(xv.w, w3.w, acc[r].w);
        }
    }

    // Publish all 4 slices (lanes write consecutive c4 -> conflict-free).
    #pragma unroll
    for (int r = 0; r < 16; ++r)
        *(float4*)&red[ks][r][c4] = acc[r];
    __syncthreads();

    // Balanced reduce: each thread sums 4 slices for 4 (r, c4) outputs.
    #pragma unroll
    for (int i = 0; i < 4; ++i) {
        const int r = ks + i * 4;   // covers r 0..15 across ks
        const float4 s0 = *(const float4*)&red[0][r][c4];
        const float4 s1 = *(const float4*)&red[1][r][c4];
        const float4 s2 = *(const float4*)&red[2][r][c4];
        const float4 s3 = *(const float4*)&red[3][r][c4];
        float4 s;
        s.x = ((s0.x + s1.x) + s2.x) + s3.x;
        s.y = ((s0.y + s1.y) + s2.y) + s3.y;
        s.z = ((s0.z + s1.z) + s2.z) + s3.z;
        s.w = ((s0.w + s1.w) + s2.w) + s3.w;
        *(float4*)(Z + ((size_t)(b0 + r) * S_LEN + t) * D_DIM + c4) = s;
    }
}

// ---------------------------------------------------------------------------
// Phase 2: sequential scan. h_t = tanh(Z[:,t,:] + h_{t-1} @ Wh[t]).
//
// v4 (structural rework; plain __syncthreads, compiler-scheduled):
//  * 256 blocks x 1024 threads, 2 batches/block -> ALL 256 CUs active
//    (v2/v3 ran 128 blocks = half the machine idle, Occupancy 12.3%).
//  * 16 waves/CU (4/SIMD) doubles memory-level parallelism for the
//    256 KB/step/CU Wh stream (the invariant cost of block-private
//    recurrence). Each wave issues its 16 float4 w-loads up-front.
//  * 16 k-slices x 16 k; h read as wave-uniform b128 broadcasts.
//  * Balanced reduce: 512 threads each own one (batch, col) output.
//  * No inline asm: v3's asm barriers + sched_barrier pinned the
//    scheduler and regressed 10% (measured).
// ---------------------------------------------------------------------------
__global__ __launch_bounds__(1024) void phase2_scan(const float* __restrict__ Wh,
                                                    float* __restrict__ ZH) {
    const int g   = blockIdx.x;
    const int b0  = g * 2;
    const int tid = threadIdx.x;
    // k-loop mapping
    const int c4  = (tid & 63) * 4;   // column base (0..252)
    const int ks  = tid >> 6;         // k-slice 0..15 (wave-uniform)
    const int kbase = ks * 16;
    // reduce mapping (threads 0..511 active)
    const int rm  = (tid >> 8) & 1;   // batch 0..1 (wave-uniform)
    const int rc  = tid & 255;        // column 0..255

    __shared__ float h[2][D_DIM];          // 2 KB   hidden state
    __shared__ float red[16][2][D_DIM];    // 32 KB  partial-sum exchange

    for (int i = tid; i < 2 * D_DIM; i += 1024) ((float*)h)[i] = 0.0f;
    __syncthreads();

    float* zrow = ZH + ((size_t)(b0 + rm) * S_LEN) * D_DIM + rc;  // used if tid<512
    const float* wb = Wh + c4;

    for (int t = 0; t < S_LEN; ++t) {
        // Z prefetch (independent of h) -> hides under the w-load/FMA phase.
        float z = 0.0f;
        if (tid < 512) z = zrow[(size_t)t * D_DIM];

        // All 16 weight rows issued up-front: 16 outstanding 1KB wave-loads
        // per wave, 256 per CU -> latency covered by MLP, not prediction.
        const float* wt = wb + (size_t)t * D_DIM * D_DIM;
        float4 w[16];
        #pragma unroll
        for (int i = 0; i < 16; ++i)
            w[i] = *(const float4*)(wt + (size_t)(kbase + i) * D_DIM);

        float4 acc0 = make_float4(0.f, 0.f, 0.f, 0.f);
        float4 acc1 = make_float4(0.f, 0.f, 0.f, 0.f);
        #pragma unroll
        for (int q = 0; q < 4; ++q) {
            const float4 ha = *(const float4*)&h[0][kbase + q * 4];  // bcast
            const float4 hb = *(const float4*)&h[1][kbase + q * 4];  // bcast
            const float4 w0 = w[q * 4 + 0];
            const float4 w1 = w[q * 4 + 1];
            const float4 w2 = w[q * 4 + 2];
            const float4 w3 = w[q * 4 + 3];
            acc0.x = fmaf(ha.x, w0.x, acc0.x);
            acc0.y = fmaf(ha.x, w0.y, acc0.y);
            acc0.z = fmaf(ha.x, w0.z, acc0.z);
            acc0.w = fmaf(ha.x, w0.w, acc0.w);
            acc0.x = fmaf(ha.y, w1.x, acc0.x);
            acc0.y = fmaf(ha.y, w1.y, acc0.y);
            acc0.z = fmaf(ha.y, w1.z, acc0.z);
            acc0.w = fmaf(ha.y, w1.w, acc0.w);
            acc0.x = fmaf(ha.z, w2.x, acc0.x);
            acc0.y = fmaf(ha.z, w2.y, acc0.y);
            acc0.z = fmaf(ha.z, w2.z, acc0.z);
            acc0.w = fmaf(ha.z, w2.w, acc0.w);
            acc0.x = fmaf(ha.w, w3.x, acc0.x);
            acc0.y = fmaf(ha.w, w3.y, acc0.y);
            acc0.z = fmaf(ha.w, w3.z, acc0.z);
            acc0.w = fmaf(ha.w, w3.w, acc0.w);

            acc1.x = fmaf(hb.x, w0.x, acc1.x);
            acc1.y = fmaf(hb.x, w0.y, acc1.y);
            acc1.z = fmaf(hb.x, w0.z, acc1.z);
            acc1.w = fmaf(hb.x, w0.w, acc1.w);
            acc1.x = fmaf(hb.y, w1.x, acc1.x);
            acc1.y = fmaf(hb.y, w1.y, acc1.y);
            acc1.z = fmaf(hb.y, w1.z, acc1.z);
            acc1.w = fmaf(hb.y, w1.w, acc1.w);
            acc1.x = fmaf(hb.z, w2.x, acc1.x);
            acc1.y = fmaf(hb.z, w2.y, acc1.y);
            acc1.z = fmaf(hb.z, w2.z, acc1.z);
            acc1.w = fmaf(hb.z, w2.w, acc1.w);
            acc1.x = fmaf(hb.w, w3.x, acc1.x);
            acc1.y = fmaf(hb.w, w3.y, acc1.y);
            acc1.z = fmaf(hb.w, w3.z, acc1.z);
            acc1.w = fmaf(hb.w, w3.w, acc1.w);
        }

        // Publish partials (lanes write consecutive c4 -> conflict-free).
        *(float4*)&red[ks][0][c4] = acc0;
        *(float4*)&red[ks][1][c4] = acc1;
        __syncthreads();

        // Balanced reduce: 512 threads, one (batch, col) each. Slices summed
        // in ascending order (k ascending overall).
        if (tid < 512) {
            float s = z;
            #pragma unroll
            for (int sl = 0; sl < 16; ++sl) s += red[sl][rm][rc];
            const float hv = tanh_fast(s);
            h[rm][rc] = hv;                      // next-step state
            zrow[(size_t)t * D_DIM] = hv;        // output over Z
        }
        __syncthreads();
    }
}

// ---------------------------------------------------------------------------
extern "C" void kernel_launch(void* const* d_in, const int* in_sizes, int n_in,
                              void* d_out, int out_size, void* d_ws, size_t ws_size,
                              hipStream_t stream) {
    const float* x  = (const float*)d_in[0];   // [B, S, D_IN]
    const float* Wx = (const float*)d_in[1];   // [S, D_IN, D_OUT]
    const float* Wh = (const float*)d_in[2];   // [S, D_OUT, D_OUT]
    float* out = (float*)d_out;                // [B, S, D_OUT]

    // Phase 1: Z = batched x @ Wx  -> d_out
    phase1_xwx<<<dim3(S_LEN, B_SZ / 16), 256, 0, stream>>>(x, Wx, out);
    // Phase 2: sequential scan over t; all 256 CUs, 2 batches/block
    phase2_scan<<<dim3(B_SZ / 2), 1024, 0, stream>>>(Wh, out);
}